// Round 1
// baseline (282.326 us; speedup 1.0000x reference)
//
#include <hip/hip_runtime.h>
#include <math.h>

// DistMult edge scoring: out[e] = sigmoid(sum_d h[u[e],d] * rel[etype[e],d] * h[v[e],d])
// N_NODES=100000, E=250000, D=384, N_ETYPES=8.
// Inputs (harness order): h (fp32), u (int32), v (int32), etype (int32), rel_weight (fp32).
// Output: fp32 [E].
//
// Layout: 32 lanes per edge (2 edges per wave64). Each lane loads 3 float4
// from each of h[u], h[v], rel row (96 float4 per 384-float row / 32 lanes),
// giving fully-coalesced 512B segments per instruction. 5-step shfl_xor
// reduction within the 32-lane group; lane 0 applies sigmoid and stores.

#define D 384
#define LANES_PER_EDGE 32

__global__ __launch_bounds__(256) void distmult_kernel(
    const float* __restrict__ h,
    const int* __restrict__ u,
    const int* __restrict__ v,
    const int* __restrict__ etype,
    const float* __restrict__ rel,
    float* __restrict__ out,
    int n_edges)
{
    int tid  = blockIdx.x * blockDim.x + threadIdx.x;
    int e    = tid >> 5;            // edge index (32 lanes per edge)
    int lane = threadIdx.x & 31;    // lane within edge group
    if (e >= n_edges) return;

    // Index loads are wave-uniform within the 32-lane group (broadcast from cache).
    const float4* hu = (const float4*)(h   + (size_t)u[e]     * D);
    const float4* hv = (const float4*)(h   + (size_t)v[e]     * D);
    const float4* r  = (const float4*)(rel + (size_t)etype[e] * D);

    float s = 0.0f;
#pragma unroll
    for (int k = 0; k < 3; ++k) {
        int j = lane + k * 32;      // 96 float4 per row, 3 per lane
        float4 a = hu[j];
        float4 b = hv[j];
        float4 c = r[j];
        s += a.x * c.x * b.x;
        s += a.y * c.y * b.y;
        s += a.z * c.z * b.z;
        s += a.w * c.w * b.w;
    }

    // Reduce across the 32-lane group.
#pragma unroll
    for (int off = 16; off >= 1; off >>= 1)
        s += __shfl_xor(s, off, 32);

    if (lane == 0)
        out[e] = 1.0f / (1.0f + __expf(-s));
}

extern "C" void kernel_launch(void* const* d_in, const int* in_sizes, int n_in,
                              void* d_out, int out_size, void* d_ws, size_t ws_size,
                              hipStream_t stream) {
    const float* h     = (const float*)d_in[0];
    const int*   u     = (const int*)  d_in[1];
    const int*   v     = (const int*)  d_in[2];
    const int*   etype = (const int*)  d_in[3];
    const float* rel   = (const float*)d_in[4];
    float* out = (float*)d_out;

    int n_edges = in_sizes[1];  // E = 250000
    int threads_total = n_edges * LANES_PER_EDGE;
    int block = 256;
    int grid = (threads_total + block - 1) / block;
    distmult_kernel<<<grid, block, 0, stream>>>(h, u, v, etype, rel, out, n_edges);
}

// Round 2
// 281.723 us; speedup vs baseline: 1.0021x; 1.0021x over previous
//
#include <hip/hip_runtime.h>
#include <math.h>

// DistMult edge scoring: out[e] = sigmoid(sum_d h[u[e],d] * rel[etype[e],d] * h[v[e],d])
// N_NODES=100000, E=250000, D=384, N_ETYPES=8.
// Inputs: h (fp32), u (int32), v (int32), etype (int32), rel_weight (fp32). Out: fp32 [E].
//
// R1: 16 lanes per edge (4 edges/wave64). Each lane loads 6 float4 per operand
// (96 float4 per row / 16 lanes) -> 18 outstanding 16B loads per lane, 2x the
// MLP of the R0 32-lane layout, to test the latency-vs-DRAM-efficiency wall.
// A 16-lane float4 segment is 256 B contiguous, so coalescing stays perfect.

#define D 384
#define LANES_PER_EDGE 16

__global__ __launch_bounds__(256) void distmult_kernel(
    const float* __restrict__ h,
    const int* __restrict__ u,
    const int* __restrict__ v,
    const int* __restrict__ etype,
    const float* __restrict__ rel,
    float* __restrict__ out,
    int n_edges)
{
    int tid  = blockIdx.x * blockDim.x + threadIdx.x;
    int e    = tid >> 4;            // edge index (16 lanes per edge)
    int lane = threadIdx.x & 15;    // lane within edge group
    if (e >= n_edges) return;

    const float4* hu = (const float4*)(h   + (size_t)u[e]     * D);
    const float4* hv = (const float4*)(h   + (size_t)v[e]     * D);
    const float4* r  = (const float4*)(rel + (size_t)etype[e] * D);

    // Issue all 18 loads before any use: separate load arrays so the compiler
    // can keep them all in flight (vmcnt-batched).
    float4 a[6], b[6], c[6];
#pragma unroll
    for (int k = 0; k < 6; ++k) {
        int j = lane + k * 16;      // 96 float4 per row, 6 per lane
        a[k] = hu[j];
        b[k] = hv[j];
        c[k] = r[j];
    }

    float s = 0.0f;
#pragma unroll
    for (int k = 0; k < 6; ++k) {
        s += a[k].x * c[k].x * b[k].x;
        s += a[k].y * c[k].y * b[k].y;
        s += a[k].z * c[k].z * b[k].z;
        s += a[k].w * c[k].w * b[k].w;
    }

    // Reduce across the 16-lane group (xor offsets < 16 stay in-group).
#pragma unroll
    for (int off = 8; off >= 1; off >>= 1)
        s += __shfl_xor(s, off);

    if (lane == 0)
        out[e] = 1.0f / (1.0f + __expf(-s));
}

extern "C" void kernel_launch(void* const* d_in, const int* in_sizes, int n_in,
                              void* d_out, int out_size, void* d_ws, size_t ws_size,
                              hipStream_t stream) {
    const float* h     = (const float*)d_in[0];
    const int*   u     = (const int*)  d_in[1];
    const int*   v     = (const int*)  d_in[2];
    const int*   etype = (const int*)  d_in[3];
    const float* rel   = (const float*)d_in[4];
    float* out = (float*)d_out;

    int n_edges = in_sizes[1];  // E = 250000
    long long threads_total = (long long)n_edges * LANES_PER_EDGE;
    int block = 256;
    int grid = (int)((threads_total + block - 1) / block);
    distmult_kernel<<<grid, block, 0, stream>>>(h, u, v, etype, rel, out, n_edges);
}

// Round 3
// 278.808 us; speedup vs baseline: 1.0126x; 1.0105x over previous
//
#include <hip/hip_runtime.h>
#include <hip/hip_bf16.h>
#include <math.h>

// DistMult edge scoring: out[e] = sigmoid(sum_d h[u[e],d] * rel[etype[e],d] * h[v[e],d])
// N_NODES=100000, E=250000, D=384, N_ETYPES=8.
// Inputs: h (fp32), u (int32), v (int32), etype (int32), rel_weight (fp32). Out: fp32 [E].
//
// R2: the R0/R1 fp32 gather is pinned at ~6.3 TB/s delivered-to-CU (768 MB of
// row gathers in 122 us) regardless of MLP -> bandwidth wall, attack bytes.
// Pass 1 converts h and rel to bf16 in d_ws (halves gather bytes; 76.8 MB bf16
// h is fully Infinity-Cache-resident). Pass 2 gathers bf16, fp32 accumulate.

#define D 384
#define N_NODES_ELEMS (100000 * 384)          // h element count
#define H_BF16_BYTES  (100000 * 384 * 2)      // 76,800,000 (16B aligned)

// ---- pass 1a: h fp32 -> bf16, packed stores. 8 floats / thread. ----
__global__ __launch_bounds__(256) void conv_h_kernel(
    const float* __restrict__ src, uint32_t* __restrict__ dst, int n8)
{
    int i = blockIdx.x * blockDim.x + threadIdx.x;
    if (i >= n8) return;
    const float4* s = (const float4*)(src) + (size_t)i * 2;
    float4 f0 = s[0];
    float4 f1 = s[1];
    uint4 o;
    // pack 2 fp32 -> 1 uint (bf16 lo|hi), round-to-nearest via __float2bfloat16
    o.x = (uint32_t)__bfloat16_as_ushort(__float2bfloat16(f0.x)) |
          ((uint32_t)__bfloat16_as_ushort(__float2bfloat16(f0.y)) << 16);
    o.y = (uint32_t)__bfloat16_as_ushort(__float2bfloat16(f0.z)) |
          ((uint32_t)__bfloat16_as_ushort(__float2bfloat16(f0.w)) << 16);
    o.z = (uint32_t)__bfloat16_as_ushort(__float2bfloat16(f1.x)) |
          ((uint32_t)__bfloat16_as_ushort(__float2bfloat16(f1.y)) << 16);
    o.w = (uint32_t)__bfloat16_as_ushort(__float2bfloat16(f1.z)) |
          ((uint32_t)__bfloat16_as_ushort(__float2bfloat16(f1.w)) << 16);
    ((uint4*)dst)[i] = o;
}

// ---- pass 2: gather bf16 rows, 16 lanes/edge, 3 uint4 (24 bf16) per operand/lane ----
__global__ __launch_bounds__(256) void distmult_kernel(
    const uint32_t* __restrict__ hb,   // bf16-packed h [N_NODES][384/2 uints]
    const uint32_t* __restrict__ rb,   // bf16-packed rel [8][192]
    const int* __restrict__ u,
    const int* __restrict__ v,
    const int* __restrict__ etype,
    float* __restrict__ out,
    int n_edges)
{
    int tid  = blockIdx.x * blockDim.x + threadIdx.x;
    int e    = tid >> 4;
    int lane = threadIdx.x & 15;
    if (e >= n_edges) return;

    const uint4* hu = (const uint4*)(hb + (size_t)u[e]     * (D / 2));
    const uint4* hv = (const uint4*)(hb + (size_t)v[e]     * (D / 2));
    const uint4* r  = (const uint4*)(rb + (size_t)etype[e] * (D / 2));

    uint4 a[3], b[3], c[3];
#pragma unroll
    for (int k = 0; k < 3; ++k) {
        int j = lane + k * 16;     // 48 uint4 per row / 16 lanes = 3
        a[k] = hu[j];
        b[k] = hv[j];
        c[k] = r[j];
    }

    float s = 0.0f;
#pragma unroll
    for (int k = 0; k < 3; ++k) {
        const uint32_t* pa = &a[k].x;
        const uint32_t* pb = &b[k].x;
        const uint32_t* pc = &c[k].x;
#pragma unroll
        for (int q = 0; q < 4; ++q) {
            float alo = __uint_as_float(pa[q] << 16);
            float ahi = __uint_as_float(pa[q] & 0xffff0000u);
            float blo = __uint_as_float(pb[q] << 16);
            float bhi = __uint_as_float(pb[q] & 0xffff0000u);
            float clo = __uint_as_float(pc[q] << 16);
            float chi = __uint_as_float(pc[q] & 0xffff0000u);
            s += alo * clo * blo;
            s += ahi * chi * bhi;
        }
    }

#pragma unroll
    for (int off = 8; off >= 1; off >>= 1)
        s += __shfl_xor(s, off);

    if (lane == 0)
        out[e] = 1.0f / (1.0f + __expf(-s));
}

extern "C" void kernel_launch(void* const* d_in, const int* in_sizes, int n_in,
                              void* d_out, int out_size, void* d_ws, size_t ws_size,
                              hipStream_t stream) {
    const float* h     = (const float*)d_in[0];
    const int*   u     = (const int*)  d_in[1];
    const int*   v     = (const int*)  d_in[2];
    const int*   etype = (const int*)  d_in[3];
    const float* rel   = (const float*)d_in[4];
    float* out = (float*)d_out;

    int n_edges = in_sizes[1];          // E = 250000
    int n_rel   = in_sizes[4];          // 8*384 = 3072

    uint32_t* hb = (uint32_t*)d_ws;                          // 76.8 MB bf16 h
    uint32_t* rb = (uint32_t*)((char*)d_ws + H_BF16_BYTES);  // 6 KB bf16 rel

    // pass 1: convert h (38.4M floats, 8/thread) and rel (3072 floats)
    int n8_h = N_NODES_ELEMS / 8;       // 4,800,000
    conv_h_kernel<<<(n8_h + 255) / 256, 256, 0, stream>>>(h, hb, n8_h);
    int n8_r = n_rel / 8;               // 384
    conv_h_kernel<<<(n8_r + 255) / 256, 256, 0, stream>>>(rel, rb, n8_r);

    // pass 2: scoring
    long long threads_total = (long long)n_edges * 16;
    int grid = (int)((threads_total + 255) / 256);
    distmult_kernel<<<grid, 256, 0, stream>>>(hb, rb, u, v, etype, out, n_edges);
}